// Round 5
// baseline (1412.695 us; speedup 1.0000x reference)
//
#include <hip/hip_runtime.h>
#include <math.h>

// VQ-VAE quantizer: N=16384 pixels, D=256, K=8192 codes.
// d_out (float32) layout: [0]=loss, [1..4194304]=z_q_x (B,C,H,W),
// [4194305]=perplexity, [4194306..+16384]=idx (as float).
//
// np-exact semantics (verified r3/r4): dist = f32(f32(sx2+se2) - 2*acc), acc
// a sequential d=0..255 fp32 FMA chain; np.argmin first-min tie-break.
// r5: X operand read from GLOBAL (wave-uniform 64B rows, L1-resident) so the
// LDS pipe carries only the E stream -> FMA-bound (floor 437 us).

#define K_EMB 8192
#define D_EMB 256
#define NPIX  16384
#define NDTOT 4194304   // NPIX * D_EMB

#define OUT_LOSS 0
#define OUT_ZQ   1
#define OUT_PERP 4194305
#define OUT_IDX  4194306

// ws layout (bytes): [0] float sse; [256] int hist[8192];
// [33024] float se2[8192]; [65792] float sx2[16384]
#define WS_HIST_OFF 256
#define WS_SE2_OFF  (256 + 32768)
#define WS_SX2_OFF  (256 + 32768 + 32768)

// argmin geometry
#define TN 64                 // pixels per block (grid = 256)
#define TK 256                // codes per k-tile
#define NSTEP 256             // (8192/TK) kt  x  (256/32) dc
#define ESTRIDE 260           // [32][260] floats; write banks 2-way (free)
#define EBUF (32 * ESTRIDE)   // floats per E buffer
#define SMEM_BYTES (2 * EBUF * 4)   // 66560 B

// ---------------------------------------------------------------------------
// sx2[n] = numpy-pairwise sum of x[n][d]^2 (two 128-blocks, 8 accumulators).
__global__ void sx2_kernel(const float* __restrict__ z,
                           float* __restrict__ sx2) {
#pragma clang fp contract(off)
    int n = blockIdx.x * 256 + threadIdx.x;
    int b = n >> 10, hw = n & 1023;
    const float* zb = z + (size_t)b * (D_EMB * 1024) + hw;
    float half[2];
#pragma unroll
    for (int h = 0; h < 2; ++h) {
        float r[8];
#pragma unroll
        for (int j = 0; j < 8; ++j) {
            float v = zb[(size_t)(h * 128 + j) * 1024];
            r[j] = v * v;
        }
        for (int i = 8; i < 128; i += 8)
#pragma unroll
            for (int j = 0; j < 8; ++j) {
                float v = zb[(size_t)(h * 128 + i + j) * 1024];
                float sq = v * v;
                r[j] = r[j] + sq;
            }
        half[h] = ((r[0] + r[1]) + (r[2] + r[3]))
                + ((r[4] + r[5]) + (r[6] + r[7]));
    }
    sx2[n] = half[0] + half[1];
}

// ---------------------------------------------------------------------------
// se2[k] = numpy-pairwise sum of emb[k][d]^2.
__global__ void se2_kernel(const float* __restrict__ emb,
                           float* __restrict__ se2) {
#pragma clang fp contract(off)
    int k = blockIdx.x * 256 + threadIdx.x;
    const float* e = emb + (size_t)k * D_EMB;
    float half[2];
#pragma unroll
    for (int h = 0; h < 2; ++h) {
        float r[8];
#pragma unroll
        for (int j = 0; j < 8; ++j) {
            float v = e[h * 128 + j];
            r[j] = v * v;
        }
        for (int i = 8; i < 128; i += 8)
#pragma unroll
            for (int j = 0; j < 8; ++j) {
                float v = e[h * 128 + i + j];
                float sq = v * v;
                r[j] = r[j] + sq;
            }
        half[h] = ((r[0] + r[1]) + (r[2] + r[3]))
                + ((r[4] + r[5]) + (r[6] + r[7]));
    }
    se2[k] = half[0] + half[1];
}

// ---------------------------------------------------------------------------
// Fused distance GEMM + argmin.
// 256 thr = 4 waves; wave w owns px [16w,16w+16); lane owns codes 4*lane+ce.
// X read from global (wave-uniform 64B rows, L1); E double-buffered in LDS.
__global__ __launch_bounds__(256, 1) void argmin_kernel(
        const float* __restrict__ z, const float* __restrict__ emb,
        const float* __restrict__ se2, const float* __restrict__ sx2,
        float* __restrict__ out_idx) {
#pragma clang fp contract(off)
    extern __shared__ float smem[];
    float* Ebase = smem;           // [2][32][ESTRIDE]

    const int t    = threadIdx.x;
    const int lane = t & 63;
    const int w    = t >> 6;
    const int n0   = blockIdx.x * TN;
    const int b    = n0 >> 10;     // HW = 1024
    const int hw0  = n0 & 1023;
    // wave-uniform base for this wave's 16 pixels
    const float* xw = z + (size_t)b * (D_EMB * 1024) + hw0 + 16 * w;

    // E staging mapping (per thread, 8 float4 per tile):
    //   c = w*64 + (it&3)*16 + (lane>>2)   code within tile
    //   q = (lane&3) + 4*(it>>2)           float4 d-chunk within 32 d
    //   load emb[(kt*TK + c)*256 + dc*32 + 4q], write Es[4q+j][c]
    //   -> global: 64B/4-lane coalesced; LDS write: 2 lanes/bank (free)
    const int sc = w * 64 + (lane >> 2);
    const int sq = lane & 3;

    // prologue: tile 0 (kt=0, dc=0) into buffer 0
    {
        float4 v[8];
#pragma unroll
        for (int it = 0; it < 8; ++it) {
            int c = sc + (it & 3) * 16;
            int q = sq + 4 * (it >> 2);
            v[it] = *(const float4*)(emb + (size_t)c * 256 + 4 * q);
        }
#pragma unroll
        for (int it = 0; it < 8; ++it) {
            int c = sc + (it & 3) * 16;
            int q = sq + 4 * (it >> 2);
            float* dst = Ebase + (4 * q) * ESTRIDE + c;
            dst[0 * ESTRIDE] = v[it].x;
            dst[1 * ESTRIDE] = v[it].y;
            dst[2 * ESTRIDE] = v[it].z;
            dst[3 * ESTRIDE] = v[it].w;
        }
    }
    __syncthreads();

    float sx2r[4][4];
#pragma unroll
    for (int g = 0; g < 4; ++g)
#pragma unroll
        for (int i = 0; i < 4; ++i)
            sx2r[g][i] = sx2[n0 + 16 * w + 4 * g + i];

    float minv[4][4];
    int   mini[4][4];
    float acc[4][4][4];
#pragma unroll
    for (int g = 0; g < 4; ++g)
#pragma unroll
        for (int i = 0; i < 4; ++i) {
            minv[g][i] = 3.0e38f; mini[g][i] = 0;
#pragma unroll
            for (int ce = 0; ce < 4; ++ce) acc[g][i][ce] = 0.0f;
        }

    int cur = 0;
    for (int s = 0; s < NSTEP; ++s) {
        const int dc = s & 7;
        const bool pf = (s + 1 < NSTEP);

        // T14: issue next E tile's global loads before compute
        float4 v[8];
        if (pf) {
            const int kt1 = (s + 1) >> 3, dc1 = (s + 1) & 7;
#pragma unroll
            for (int it = 0; it < 8; ++it) {
                int c = sc + (it & 3) * 16;
                int q = sq + 4 * (it >> 2);
                v[it] = *(const float4*)(emb
                        + (size_t)(kt1 * TK + c) * 256 + dc1 * 32 + 4 * q);
            }
        }

        // compute: 32 d, 64 FMA each; d-chain ascending (np/BLAS order).
        // X: wave-uniform global loads (L1-resident, one 16B request/wave);
        // E: one lane-varying ds_read_b128 per d.
        const float* Ecur = Ebase + cur * EBUF;
#pragma unroll 8
        for (int d = 0; d < 32; ++d) {
            const float* xr = xw + (size_t)(dc * 32 + d) * 1024;
            float4 x0 = *(const float4*)(xr + 0);
            float4 x1 = *(const float4*)(xr + 4);
            float4 x2 = *(const float4*)(xr + 8);
            float4 x3 = *(const float4*)(xr + 12);
            float4 e  = *(const float4*)&Ecur[d * ESTRIDE + 4 * lane];
            float xv[4][4] = {{x0.x, x0.y, x0.z, x0.w},
                              {x1.x, x1.y, x1.z, x1.w},
                              {x2.x, x2.y, x2.z, x2.w},
                              {x3.x, x3.y, x3.z, x3.w}};
            float ev[4] = {e.x, e.y, e.z, e.w};
#pragma unroll
            for (int g = 0; g < 4; ++g)
#pragma unroll
                for (int i = 0; i < 4; ++i)
#pragma unroll
                    for (int ce = 0; ce < 4; ++ce)
                        acc[g][i][ce] = __builtin_fmaf(
                            xv[g][i], ev[ce], acc[g][i][ce]);
        }

        // end of a k-tile: dist + argmin update, reset acc
        if ((s & 7) == 7) {
            const int kt = s >> 3;
            float4 s4 = *(const float4*)&se2[kt * TK + 4 * lane];
            float se2v[4] = {s4.x, s4.y, s4.z, s4.w};
#pragma unroll
            for (int g = 0; g < 4; ++g)
#pragma unroll
                for (int i = 0; i < 4; ++i)
#pragma unroll
                    for (int ce = 0; ce < 4; ++ce) {
                        int k = kt * TK + 4 * lane + ce;
                        float A = sx2r[g][i] + se2v[ce];
                        float dist = A - 2.0f * acc[g][i][ce];
                        if (dist < minv[g][i]) {
                            minv[g][i] = dist;
                            mini[g][i] = k;
                        }
                        acc[g][i][ce] = 0.0f;
                    }
        }

        // write prefetched tile into the other buffer
        if (pf) {
            float* Enxt = Ebase + (cur ^ 1) * EBUF;
#pragma unroll
            for (int it = 0; it < 8; ++it) {
                int c = sc + (it & 3) * 16;
                int q = sq + 4 * (it >> 2);
                float* dst = Enxt + (4 * q) * ESTRIDE + c;
                dst[0 * ESTRIDE] = v[it].x;
                dst[1 * ESTRIDE] = v[it].y;
                dst[2 * ESTRIDE] = v[it].z;
                dst[3 * ESTRIDE] = v[it].w;
            }
        }
        __syncthreads();
        cur ^= 1;
    }

    // lexicographic (value, index) merge across the 64 lanes of the wave
#pragma unroll
    for (int g = 0; g < 4; ++g)
#pragma unroll
        for (int i = 0; i < 4; ++i) {
            float vv = minv[g][i];
            int   ki = mini[g][i];
#pragma unroll
            for (int m = 1; m <= 32; m <<= 1) {
                float ov = __shfl_xor(vv, m, 64);
                int   oi = __shfl_xor(ki, m, 64);
                if (ov < vv || (ov == vv && oi < ki)) { vv = ov; ki = oi; }
            }
            if (lane == 0)
                out_idx[n0 + 16 * w + 4 * g + i] = (float)ki;
        }
}

// ---------------------------------------------------------------------------
// Histogram of final indices, for perplexity.
__global__ void hist_kernel(const float* __restrict__ idxf,
                            int* __restrict__ hist) {
    int n = blockIdx.x * 256 + threadIdx.x;
    atomicAdd(&hist[(int)idxf[n]], 1);
}

// ---------------------------------------------------------------------------
// Gather quantized vectors, write z_q_x, accumulate sum of squared errors.
__global__ void quantize_kernel(const float* __restrict__ z,
                                const float* __restrict__ emb,
                                const float* __restrict__ idxf,
                                float* __restrict__ zq,
                                float* __restrict__ sse) {
    int o = (blockIdx.x * 256 + threadIdx.x) * 4;
    int hw = o & 1023;
    int c  = (o >> 10) & 255;
    int b  = o >> 18;
    int nbase = b * 1024 + hw;
    float4 x = *(const float4*)(z + o);
    float q0 = emb[(size_t)((int)idxf[nbase + 0]) * D_EMB + c];
    float q1 = emb[(size_t)((int)idxf[nbase + 1]) * D_EMB + c];
    float q2 = emb[(size_t)((int)idxf[nbase + 2]) * D_EMB + c];
    float q3 = emb[(size_t)((int)idxf[nbase + 3]) * D_EMB + c];
    float4 q = make_float4(q0, q1, q2, q3);
    *(float4*)(zq + o) = q;
    float d0 = q.x - x.x, d1 = q.y - x.y, d2 = q.z - x.z, d3 = q.w - x.w;
    float s = d0 * d0 + d1 * d1 + d2 * d2 + d3 * d3;
#pragma unroll
    for (int m = 1; m < 64; m <<= 1) s += __shfl_xor(s, m, 64);
    __shared__ float red[4];
    int lane = threadIdx.x & 63, wv = threadIdx.x >> 6;
    if (lane == 0) red[wv] = s;
    __syncthreads();
    if (threadIdx.x == 0)
        atomicAdd(sse, red[0] + red[1] + red[2] + red[3]);
}

// ---------------------------------------------------------------------------
__global__ void finalize_kernel(const int* __restrict__ hist,
                                const float* __restrict__ sse,
                                float* __restrict__ out) {
    float s = 0.0f;
    for (int i = threadIdx.x; i < K_EMB; i += 256) {
        float p = (float)hist[i] * (1.0f / (float)NPIX);
        s += p * logf(p + 1e-10f);
    }
#pragma unroll
    for (int m = 1; m < 64; m <<= 1) s += __shfl_xor(s, m, 64);
    __shared__ float red[4];
    int lane = threadIdx.x & 63, wv = threadIdx.x >> 6;
    if (lane == 0) red[wv] = s;
    __syncthreads();
    if (threadIdx.x == 0) {
        float H = -(red[0] + red[1] + red[2] + red[3]);
        out[OUT_PERP] = expf(H);
        out[OUT_LOSS] = 1.25f * sse[0] / (float)NDTOT;
    }
}

// ---------------------------------------------------------------------------
extern "C" void kernel_launch(void* const* d_in, const int* in_sizes, int n_in,
                              void* d_out, int out_size, void* d_ws, size_t ws_size,
                              hipStream_t stream) {
    const float* z   = (const float*)d_in[0];   // [16,256,32,32]
    const float* emb = (const float*)d_in[1];   // [8192,256]
    float* out = (float*)d_out;
    char*  ws  = (char*)d_ws;
    float* sse  = (float*)(ws);
    int*   hist = (int*)(ws + WS_HIST_OFF);
    float* se2  = (float*)(ws + WS_SE2_OFF);
    float* sx2  = (float*)(ws + WS_SX2_OFF);

    // allow >64KB dynamic LDS (idempotent; capture-safe host call)
    static int attr_done = 0;
    if (!attr_done) {
        (void)hipFuncSetAttribute((const void*)argmin_kernel,
                                  hipFuncAttributeMaxDynamicSharedMemorySize,
                                  SMEM_BYTES);
        attr_done = 1;
    }

    // zero sse + hist every call (graph replays don't re-poison)
    hipMemsetAsync(d_ws, 0, WS_SE2_OFF, stream);

    sx2_kernel<<<NPIX / 256, 256, 0, stream>>>(z, sx2);
    se2_kernel<<<K_EMB / 256, 256, 0, stream>>>(emb, se2);
    argmin_kernel<<<NPIX / TN, 256, SMEM_BYTES, stream>>>(z, emb, se2, sx2,
                                                          out + OUT_IDX);
    hist_kernel<<<NPIX / 256, 256, 0, stream>>>(out + OUT_IDX, hist);
    quantize_kernel<<<NDTOT / (256 * 4), 256, 0, stream>>>(
        z, emb, out + OUT_IDX, out + OUT_ZQ, sse);
    finalize_kernel<<<1, 256, 0, stream>>>(hist, sse, out);
}

// Round 6
// 1057.989 us; speedup vs baseline: 1.3353x; 1.3353x over previous
//
#include <hip/hip_runtime.h>
#include <math.h>

// VQ-VAE quantizer: N=16384 pixels, D=256, K=8192 codes.
// d_out (float32) layout: [0]=loss, [1..4194304]=z_q_x (B,C,H,W),
// [4194305]=perplexity, [4194306..+16384]=idx (as float).
//
// np-exact semantics (verified r3/r4): dist = f32(f32(sx2+se2) - f32(2*acc)),
// acc = sequential d=0..255 fp32 FMA chain; np.argmin first-min tie-break.
// r6: lane tile 8px x 16codes (R = LDS/FMA ~ 1.13), waves own distinct code
// quarters, X persistent LDS, E dbuf with staggered conflict-free layout.

#define K_EMB 8192
#define D_EMB 256
#define NPIX  16384
#define NDTOT 4194304   // NPIX * D_EMB

#define OUT_LOSS 0
#define OUT_ZQ   1
#define OUT_PERP 4194305
#define OUT_IDX  4194306

// ws layout (bytes): [0] float sse; [256] int hist[8192];
// [33024] float se2[8192]; [65792] float sx2[16384]
#define WS_HIST_OFF 256
#define WS_SE2_OFF  (256 + 32768)
#define WS_SX2_OFF  (256 + 32768 + 32768)

// argmin geometry
#define TN 64                  // pixels per block (grid = 256)
#define TKT 512                // codes per k-tile (4 waves x 128)
#define DC 16                  // d per step
#define NSTEP 256              // 16 kt x 16 dc
#define XSTRIDE 68             // X [256][68] floats
#define XWORDS (256 * XSTRIDE)
#define EROW 644               // E row: 512 data + stagger pads + row-shift pad
#define EBUF (DC * EROW)
#define SMEM_WORDS (XWORDS + 2 * EBUF)
#define SMEM_BYTES (SMEM_WORDS * 4)   // 152064 B

// ---------------------------------------------------------------------------
// sx2[n] = numpy-pairwise sum of x[n][d]^2 (two 128-blocks, 8 accumulators).
__global__ void sx2_kernel(const float* __restrict__ z,
                           float* __restrict__ sx2) {
#pragma clang fp contract(off)
    int n = blockIdx.x * 256 + threadIdx.x;
    int b = n >> 10, hw = n & 1023;
    const float* zb = z + (size_t)b * (D_EMB * 1024) + hw;
    float half[2];
#pragma unroll
    for (int h = 0; h < 2; ++h) {
        float r[8];
#pragma unroll
        for (int j = 0; j < 8; ++j) {
            float v = zb[(size_t)(h * 128 + j) * 1024];
            r[j] = v * v;
        }
        for (int i = 8; i < 128; i += 8)
#pragma unroll
            for (int j = 0; j < 8; ++j) {
                float v = zb[(size_t)(h * 128 + i + j) * 1024];
                float sq = v * v;
                r[j] = r[j] + sq;
            }
        half[h] = ((r[0] + r[1]) + (r[2] + r[3]))
                + ((r[4] + r[5]) + (r[6] + r[7]));
    }
    sx2[n] = half[0] + half[1];
}

// ---------------------------------------------------------------------------
// se2[k] = numpy-pairwise sum of emb[k][d]^2.
__global__ void se2_kernel(const float* __restrict__ emb,
                           float* __restrict__ se2) {
#pragma clang fp contract(off)
    int k = blockIdx.x * 256 + threadIdx.x;
    const float* e = emb + (size_t)k * D_EMB;
    float half[2];
#pragma unroll
    for (int h = 0; h < 2; ++h) {
        float r[8];
#pragma unroll
        for (int j = 0; j < 8; ++j) {
            float v = e[h * 128 + j];
            r[j] = v * v;
        }
        for (int i = 8; i < 128; i += 8)
#pragma unroll
            for (int j = 0; j < 8; ++j) {
                float v = e[h * 128 + i + j];
                float sq = v * v;
                r[j] = r[j] + sq;
            }
        half[h] = ((r[0] + r[1]) + (r[2] + r[3]))
                + ((r[4] + r[5]) + (r[6] + r[7]));
    }
    se2[k] = half[0] + half[1];
}

// ---------------------------------------------------------------------------
// Fused distance GEMM + argmin.
// 256 thr = 4 waves. Wave w owns code quarter [128w,128w+128) of each k-tile;
// every wave covers all 64 px. Lane = 8*ml + nl: ml -> px block 8*ml..+8,
// nl -> code chunk 16*nl..+16. Per-lane tile 8px x 16codes (128 FMA/d).
// X persistent [256][68]; E dbuf [2][16][644] staggered: ca = c + 4*(c>>4).
__global__ __launch_bounds__(256, 1) void argmin_kernel(
        const float* __restrict__ z, const float* __restrict__ emb,
        const float* __restrict__ se2, const float* __restrict__ sx2,
        float* __restrict__ out_idx) {
#pragma clang fp contract(off)
    extern __shared__ float smem[];
    float* Xs    = smem;               // [256][XSTRIDE]
    float* Ebase = smem + XWORDS;      // [2][DC][EROW]

    const int t    = threadIdx.x;
    const int lane = t & 63;
    const int w    = t >> 6;
    const int nl   = lane & 7;
    const int ml   = lane >> 3;
    const int n0   = blockIdx.x * TN;
    const int b    = n0 >> 10;         // HW = 1024
    const int hw0  = n0 & 1023;
    const float* zb = z + (size_t)b * (D_EMB * 1024) + hw0;

    // ---- stage X (64 px x 256 d) once: 16 float4 per thread ----
    {
        int px4 = t & 15;
        int dr  = t >> 4;
#pragma unroll
        for (int r = 0; r < 16; ++r) {
            int d = 16 * r + dr;
            float4 v = *(const float4*)(zb + (size_t)d * 1024 + 4 * px4);
            *(float4*)&Xs[d * XSTRIDE + 4 * px4] = v;
        }
    }

    // E staging map: thread -> (sq = d-chunk, scl = base code); pass p gives
    // c = scl + 64p. Write row 4*sq+j, col ca = c + 4*(c>>4).
    const int sq  = t & 3;
    const int scl = t >> 2;

    // prologue: step 0 (kt=0, dc=0) into buffer 0
    {
        float4 v[8];
#pragma unroll
        for (int p = 0; p < 8; ++p)
            v[p] = *(const float4*)(emb + (size_t)(scl + 64 * p) * 256 + 4 * sq);
#pragma unroll
        for (int p = 0; p < 8; ++p) {
            int c  = scl + 64 * p;
            int ca = c + 4 * (c >> 4);
            float* dst = Ebase + (4 * sq) * EROW + ca;
            dst[0 * EROW] = v[p].x;
            dst[1 * EROW] = v[p].y;
            dst[2 * EROW] = v[p].z;
            dst[3 * EROW] = v[p].w;
        }
    }
    __syncthreads();

    float sx2r[8];
#pragma unroll
    for (int i = 0; i < 8; ++i)
        sx2r[i] = sx2[n0 + 8 * ml + i];

    float minv[8];
    int   mini[8];
    float acc[8][16];
#pragma unroll
    for (int i = 0; i < 8; ++i) {
        minv[i] = 3.0e38f; mini[i] = 0;
#pragma unroll
        for (int ce = 0; ce < 16; ++ce) acc[i][ce] = 0.0f;
    }

    // E read base: addr(d, ce) = d*EROW + 160*w + 20*nl + ce  (ce in [0,16))
    const int erd = 160 * w + 20 * nl;

    int cur = 0;
    for (int s = 0; s < NSTEP; ++s) {
        const bool pf = (s + 1 < NSTEP);

        // T14: issue next E tile's global loads before compute
        float4 v[8];
        if (pf) {
            const int kt1 = (s + 1) >> 4, dc1 = (s + 1) & 15;
            const float* src = emb + (size_t)kt1 * TKT * 256 + dc1 * 16 + 4 * sq;
#pragma unroll
            for (int p = 0; p < 8; ++p)
                v[p] = *(const float4*)(src + (size_t)(scl + 64 * p) * 256);
        }

        // compute: DC=16 d, 128 FMA each; global d = (s&15)*16 + d ascending
        const float* Ec  = Ebase + cur * EBUF;
        const int    dg0 = (s & 15) * 16;
#pragma unroll
        for (int d = 0; d < DC; ++d) {
            const float* xr = &Xs[(dg0 + d) * XSTRIDE + 8 * ml];
            float4 xa = *(const float4*)(xr + 0);
            float4 xb = *(const float4*)(xr + 4);
            const float* er = &Ec[d * EROW + erd];
            float4 e0 = *(const float4*)(er + 0);
            float4 e1 = *(const float4*)(er + 4);
            float4 e2 = *(const float4*)(er + 8);
            float4 e3 = *(const float4*)(er + 12);
            float xv[8]  = {xa.x, xa.y, xa.z, xa.w, xb.x, xb.y, xb.z, xb.w};
            float ev[16] = {e0.x, e0.y, e0.z, e0.w, e1.x, e1.y, e1.z, e1.w,
                            e2.x, e2.y, e2.z, e2.w, e3.x, e3.y, e3.z, e3.w};
#pragma unroll
            for (int i = 0; i < 8; ++i)
#pragma unroll
                for (int ce = 0; ce < 16; ++ce)
                    acc[i][ce] = __builtin_fmaf(xv[i], ev[ce], acc[i][ce]);
        }

        // end of k-tile: dist + argmin update (k ascending), reset acc
        if ((s & 15) == 15) {
            const int kt = s >> 4;
            const int kb = kt * TKT + 128 * w + 16 * nl;
            const float* sp = &se2[kb];
            float4 s0 = *(const float4*)(sp + 0);
            float4 s1 = *(const float4*)(sp + 4);
            float4 s2 = *(const float4*)(sp + 8);
            float4 s3 = *(const float4*)(sp + 12);
            float se2v[16] = {s0.x, s0.y, s0.z, s0.w, s1.x, s1.y, s1.z, s1.w,
                              s2.x, s2.y, s2.z, s2.w, s3.x, s3.y, s3.z, s3.w};
#pragma unroll
            for (int i = 0; i < 8; ++i)
#pragma unroll
                for (int ce = 0; ce < 16; ++ce) {
                    float A = sx2r[i] + se2v[ce];
                    float dist = A - 2.0f * acc[i][ce];
                    if (dist < minv[i]) {
                        minv[i] = dist;
                        mini[i] = kb + ce;
                    }
                    acc[i][ce] = 0.0f;
                }
        }

        // write prefetched tile into the other buffer
        if (pf) {
            float* En = Ebase + (cur ^ 1) * EBUF;
#pragma unroll
            for (int p = 0; p < 8; ++p) {
                int c  = scl + 64 * p;
                int ca = c + 4 * (c >> 4);
                float* dst = En + (4 * sq) * EROW + ca;
                dst[0 * EROW] = v[p].x;
                dst[1 * EROW] = v[p].y;
                dst[2 * EROW] = v[p].z;
                dst[3 * EROW] = v[p].w;
            }
        }
        __syncthreads();
        cur ^= 1;
    }

    // merge over the 8 nl lanes (codes) -> per-px (v,k), lexicographic
#pragma unroll
    for (int i = 0; i < 8; ++i) {
        float vv = minv[i];
        int   ki = mini[i];
#pragma unroll
        for (int m = 1; m <= 4; m <<= 1) {
            float ov = __shfl_xor(vv, m, 64);
            int   oi = __shfl_xor(ki, m, 64);
            if (ov < vv || (ov == vv && oi < ki)) { vv = ov; ki = oi; }
        }
        minv[i] = vv; mini[i] = ki;
    }

    // cross-wave merge via LDS (reuse smem; all E/X reads are done)
    float* Vred = smem;                 // [4][64]
    int*   Kred = (int*)(smem + 256);   // [4][64]
    if (nl == 0) {
#pragma unroll
        for (int i = 0; i < 8; ++i) {
            int pl = 8 * ml + i;
            Vred[w * 64 + pl] = minv[i];
            Kred[w * 64 + pl] = mini[i];
        }
    }
    __syncthreads();
    if (t < 64) {
        float vv = Vred[t];
        int   ki = Kred[t];
#pragma unroll
        for (int ww = 1; ww < 4; ++ww) {
            float ov = Vred[ww * 64 + t];
            int   oi = Kred[ww * 64 + t];
            if (ov < vv || (ov == vv && oi < ki)) { vv = ov; ki = oi; }
        }
        out_idx[n0 + t] = (float)ki;
    }
}

// ---------------------------------------------------------------------------
// Histogram of final indices, for perplexity.
__global__ void hist_kernel(const float* __restrict__ idxf,
                            int* __restrict__ hist) {
    int n = blockIdx.x * 256 + threadIdx.x;
    atomicAdd(&hist[(int)idxf[n]], 1);
}

// ---------------------------------------------------------------------------
// Gather quantized vectors, write z_q_x, accumulate sum of squared errors.
__global__ void quantize_kernel(const float* __restrict__ z,
                                const float* __restrict__ emb,
                                const float* __restrict__ idxf,
                                float* __restrict__ zq,
                                float* __restrict__ sse) {
    int o = (blockIdx.x * 256 + threadIdx.x) * 4;
    int hw = o & 1023;
    int c  = (o >> 10) & 255;
    int b  = o >> 18;
    int nbase = b * 1024 + hw;
    float4 x = *(const float4*)(z + o);
    float q0 = emb[(size_t)((int)idxf[nbase + 0]) * D_EMB + c];
    float q1 = emb[(size_t)((int)idxf[nbase + 1]) * D_EMB + c];
    float q2 = emb[(size_t)((int)idxf[nbase + 2]) * D_EMB + c];
    float q3 = emb[(size_t)((int)idxf[nbase + 3]) * D_EMB + c];
    float4 q = make_float4(q0, q1, q2, q3);
    *(float4*)(zq + o) = q;
    float d0 = q.x - x.x, d1 = q.y - x.y, d2 = q.z - x.z, d3 = q.w - x.w;
    float s = d0 * d0 + d1 * d1 + d2 * d2 + d3 * d3;
#pragma unroll
    for (int m = 1; m < 64; m <<= 1) s += __shfl_xor(s, m, 64);
    __shared__ float red[4];
    int lane = threadIdx.x & 63, wv = threadIdx.x >> 6;
    if (lane == 0) red[wv] = s;
    __syncthreads();
    if (threadIdx.x == 0)
        atomicAdd(sse, red[0] + red[1] + red[2] + red[3]);
}

// ---------------------------------------------------------------------------
__global__ void finalize_kernel(const int* __restrict__ hist,
                                const float* __restrict__ sse,
                                float* __restrict__ out) {
    float s = 0.0f;
    for (int i = threadIdx.x; i < K_EMB; i += 256) {
        float p = (float)hist[i] * (1.0f / (float)NPIX);
        s += p * logf(p + 1e-10f);
    }
#pragma unroll
    for (int m = 1; m < 64; m <<= 1) s += __shfl_xor(s, m, 64);
    __shared__ float red[4];
    int lane = threadIdx.x & 63, wv = threadIdx.x >> 6;
    if (lane == 0) red[wv] = s;
    __syncthreads();
    if (threadIdx.x == 0) {
        float H = -(red[0] + red[1] + red[2] + red[3]);
        out[OUT_PERP] = expf(H);
        out[OUT_LOSS] = 1.25f * sse[0] / (float)NDTOT;
    }
}

// ---------------------------------------------------------------------------
extern "C" void kernel_launch(void* const* d_in, const int* in_sizes, int n_in,
                              void* d_out, int out_size, void* d_ws, size_t ws_size,
                              hipStream_t stream) {
    const float* z   = (const float*)d_in[0];   // [16,256,32,32]
    const float* emb = (const float*)d_in[1];   // [8192,256]
    float* out = (float*)d_out;
    char*  ws  = (char*)d_ws;
    float* sse  = (float*)(ws);
    int*   hist = (int*)(ws + WS_HIST_OFF);
    float* se2  = (float*)(ws + WS_SE2_OFF);
    float* sx2  = (float*)(ws + WS_SX2_OFF);

    // allow >64KB dynamic LDS (idempotent; capture-safe host call)
    static int attr_done = 0;
    if (!attr_done) {
        (void)hipFuncSetAttribute((const void*)argmin_kernel,
                                  hipFuncAttributeMaxDynamicSharedMemorySize,
                                  SMEM_BYTES);
        attr_done = 1;
    }

    // zero sse + hist every call (graph replays don't re-poison)
    hipMemsetAsync(d_ws, 0, WS_SE2_OFF, stream);

    sx2_kernel<<<NPIX / 256, 256, 0, stream>>>(z, sx2);
    se2_kernel<<<K_EMB / 256, 256, 0, stream>>>(emb, se2);
    argmin_kernel<<<NPIX / TN, 256, SMEM_BYTES, stream>>>(z, emb, se2, sx2,
                                                          out + OUT_IDX);
    hist_kernel<<<NPIX / 256, 256, 0, stream>>>(out + OUT_IDX, hist);
    quantize_kernel<<<NDTOT / (256 * 4), 256, 0, stream>>>(
        z, emb, out + OUT_IDX, out + OUT_ZQ, sse);
    finalize_kernel<<<1, 256, 0, stream>>>(hist, sse, out);
}